// Round 5
// baseline (374.079 us; speedup 1.0000x reference)
//
#include <hip/hip_runtime.h>
#include <hip/hip_bf16.h>

// Causal flash attention, B=4 H=16 S=2048 DK=DV=128, fp32 in/out, bf16 MFMA compute.
// R7: dispatch-order balance. R6 measured OccupancyPercent 13.8% (~1.1 of 2
// possible blocks resident) -- work skew is 16:1 (ntiles=2qt+2) and the old
// order put heavy blocks at the end of every bh-group. New order interleaves
// heavy/light within each bh-group: qt = {15,0,14,1,...,8,7}, so every
// temporal window of the dispatch averages ~17 tiles and the drain tail is
// medium, not heavy. bh-clustering + XCD pinning preserved (L2 locality).
// Also T5: s_setprio(1) around QK^T and PV MFMA clusters (2 blocks/CU at
// different phases -> scheduler favors the MFMA-issuing wave; m191 +4-7%).
// Structure otherwise identical to R6 (in-register P transpose, K dbuf +
// cross-barrier prefetch, lgkmcnt-only drains). LDS 53248 B.

#define S_LEN 2048
#define DKC   128
#define DVC   128
#define BM    128   // q rows per block (32 per wave)
#define BN    64
#define KPAD  136   // K LDS row stride (bf16): 272B -> b128-aligned reads, 2-way banks
#define VPAD  72    // Vt LDS row stride:      144B -> b128-aligned reads, 2-way banks

typedef __bf16 bf16;
typedef bf16  bf16x4 __attribute__((ext_vector_type(4)));
typedef bf16  bf16x8 __attribute__((ext_vector_type(8)));
typedef float f32x4  __attribute__((ext_vector_type(4)));
typedef unsigned int u32;
typedef u32 u32x4 __attribute__((ext_vector_type(4)));

__global__ __launch_bounds__(256, 2)
void fa_kernel(const float* __restrict__ Q, const float* __restrict__ K,
               const float* __restrict__ V, float* __restrict__ O) {
  __shared__ bf16 Klds[2][BN][KPAD];     // double-buffered [key][d]
  __shared__ bf16 Vlds[DVC][VPAD];       // transposed: [dv][key], single buffer

  const int tid  = threadIdx.x;
  const int w    = tid >> 6;
  const int lane = tid & 63;
  const int quad = lane >> 4;
  const int l16  = lane & 15;

  // XCD-aware swizzle: bh pinned to one XCD (lin%8); bh-group clustered for L2;
  // heavy/light INTERLEAVED within the group so the temporal mix is balanced.
  const int lin = blockIdx.x;
  const int xcd = lin & 7;
  const int idx = lin >> 3;            // 0..127
  const int j   = idx & 15;
  const int qt  = (j & 1) ? (j >> 1) : (15 - (j >> 1));  // 15,0,14,1,...,8,7
  const int bh  = xcd + 8 * (idx >> 4);

  const int q0 = qt * BM;
  const size_t base = (size_t)bh * S_LEN * DKC;
  const float* Qp = Q + base;
  const float* Kp = K + base;
  const float* Vp = V + base;
  float*       Op = O + base;

  const float SCALE2 = 0.08838834764831845f * 1.4426950408889634f; // 1/sqrt(128)*log2e

  // ---- Q fragments, 2 groups of 16 rows (B-layout for swapped QK^T:
  //      lane holds Q[q=l16][k=quad*8+j], which is B[k][q] with col=q=l16) ----
  bf16x8 qf[2][4];
#pragma unroll
  for (int g = 0; g < 2; ++g) {
    const float* qrow = Qp + (size_t)(q0 + w * 32 + g * 16 + l16) * DKC;
#pragma unroll
    for (int c = 0; c < 4; ++c) {
      const float* pq = qrow + c * 32 + quad * 8;
      float4 x = *(const float4*)pq;
      float4 y = *(const float4*)(pq + 4);
      bf16x8 f;
      f[0] = (bf16)(x.x * SCALE2); f[1] = (bf16)(x.y * SCALE2);
      f[2] = (bf16)(x.z * SCALE2); f[3] = (bf16)(x.w * SCALE2);
      f[4] = (bf16)(y.x * SCALE2); f[5] = (bf16)(y.y * SCALE2);
      f[6] = (bf16)(y.z * SCALE2); f[7] = (bf16)(y.w * SCALE2);
      qf[g][c] = f;
    }
  }

  f32x4 oacc[2][8];
#pragma unroll
  for (int g = 0; g < 2; ++g)
#pragma unroll
    for (int n = 0; n < 8; ++n)
#pragma unroll
      for (int r = 0; r < 4; ++r) oacc[g][n][r] = 0.0f;
  float lsum[2] = {0.0f, 0.0f};   // per-lane denominator for q = l16 (per g-group)

  // staging addresses (fixed per thread)
  const int krow = tid >> 5;          // 0..7 (+ i*8)
  const int kcol = (tid & 31) * 4;    // 0..124
  const int vk   = tid & 31;          // + 32*(i&1)
  const int vd   = tid >> 5;          // (+ 8*(i>>1))*4

  const int ntiles = 2 * qt + 2;

  // ---- prologue: issue tile-0 staging loads ----
  float4 kx[8], vx[8];
#pragma unroll
  for (int i = 0; i < 8; ++i)
    kx[i] = *(const float4*)(Kp + (size_t)(krow + i * 8) * DKC + kcol);
#pragma unroll
  for (int i = 0; i < 8; ++i) {
    int k  = vk + 32 * (i & 1);
    int d4 = (vd + 8 * (i >> 1)) * 4;
    vx[i] = *(const float4*)(Vp + (size_t)k * DVC + d4);
  }

  for (int t = 0; t < ntiles; ++t) {
    const int buf = t & 1;
    const int kvb = t * BN;

    // ---- K write (pre-barrier is safe: other waves read the OTHER K buffer) ----
#pragma unroll
    for (int i = 0; i < 8; ++i) {
      bf16x4 k4;
      k4[0] = (bf16)kx[i].x; k4[1] = (bf16)kx[i].y;
      k4[2] = (bf16)kx[i].z; k4[3] = (bf16)kx[i].w;
      *(bf16x4*)&Klds[buf][krow + i * 8][kcol] = k4;
    }
    // ---- K prefetch t+1: stays in flight across the raw barriers below ----
    if (t + 1 < ntiles) {
      const int kvb2 = kvb + BN;
#pragma unroll
      for (int i = 0; i < 8; ++i)
        kx[i] = *(const float4*)(Kp + (size_t)(kvb2 + krow + i * 8) * DKC + kcol);
    }
    // barrier1: all waves done with compute(t-1) (V reads) and K writes visible.
    // lgkmcnt-only drain: do NOT drain vmcnt (prefetch must survive).
    asm volatile("s_waitcnt lgkmcnt(0)\n\ts_barrier" ::: "memory");

    // ---- V write (single buffer; compiler emits a COUNTED vmcnt wait for vx) ----
#pragma unroll
    for (int i = 0; i < 8; ++i) {
      int k  = vk + 32 * (i & 1);
      int d4 = (vd + 8 * (i >> 1)) * 4;
      Vlds[d4 + 0][k] = (bf16)vx[i].x;
      Vlds[d4 + 1][k] = (bf16)vx[i].y;
      Vlds[d4 + 2][k] = (bf16)vx[i].z;
      Vlds[d4 + 3][k] = (bf16)vx[i].w;
    }
    // barrier2: V writes visible before any wave reads the tile.
    asm volatile("s_waitcnt lgkmcnt(0)\n\ts_barrier" ::: "memory");

    // ---- V prefetch t+1 (latency hidden under QK^T + softmax + PV) ----
    if (t + 1 < ntiles) {
      const int kvb2 = kvb + BN;
#pragma unroll
      for (int i = 0; i < 8; ++i) {
        int k  = vk + 32 * (i & 1);
        int d4 = (vd + 8 * (i >> 1)) * 4;
        vx[i] = *(const float4*)(Vp + (size_t)(kvb2 + k) * DVC + d4);
      }
    }

    // ---- S^T = K Q^T (swapped): per n-subtile, col=q=l16, row=key=quad*4+r.
    //      Fused mask + exp2 + denominator + bf16 pack (sacc lives 8 regs). ----
    u32 W[2][4][2];   // packed bf16 P: [g][n][lo/hi], lane quad holds keys quad*4+0..3
#pragma unroll
    for (int n = 0; n < 4; ++n) {
      f32x4 sacc[2];
#pragma unroll
      for (int g = 0; g < 2; ++g)
#pragma unroll
        for (int r = 0; r < 4; ++r) sacc[g][r] = 0.0f;
      __builtin_amdgcn_s_setprio(1);
#pragma unroll
      for (int c = 0; c < 4; ++c) {
        bf16x8 kf = *(const bf16x8*)&Klds[buf][n * 16 + l16][c * 32 + quad * 8];
        sacc[0] = __builtin_amdgcn_mfma_f32_16x16x32_bf16(kf, qf[0][c], sacc[0], 0, 0, 0);
        sacc[1] = __builtin_amdgcn_mfma_f32_16x16x32_bf16(kf, qf[1][c], sacc[1], 0, 0, 0);
      }
      __builtin_amdgcn_s_setprio(0);
      // causal mask: only the last TWO tiles can touch any wave's diagonal
      if (t >= ntiles - 2) {
        const int kg = kvb + n * 16 + quad * 4;
#pragma unroll
        for (int g = 0; g < 2; ++g) {
          const int qg = q0 + w * 32 + g * 16 + l16;
#pragma unroll
          for (int r = 0; r < 4; ++r)
            if (kg + r > qg) sacc[g][r] = -1e30f;  // exp2 -> 0
        }
      }
#pragma unroll
      for (int g = 0; g < 2; ++g) {
        float p0 = exp2f(sacc[g][0]);
        float p1 = exp2f(sacc[g][1]);
        float p2 = exp2f(sacc[g][2]);
        float p3 = exp2f(sacc[g][3]);
        lsum[g] += (p0 + p1) + (p2 + p3);
        asm("v_cvt_pk_bf16_f32 %0, %1, %2" : "=v"(W[g][n][0]) : "v"(p0), "v"(p1));
        asm("v_cvt_pk_bf16_f32 %0, %1, %2" : "=v"(W[g][n][1]) : "v"(p2), "v"(p3));
      }
    }

    // ---- P: C-layout -> A-layout IN REGISTERS (no LDS round-trip).
    //  permlane32_swap(P0,P1): P0'=[P0.r0,P0.r1,P1.r0,P1.r1], P1'=[P0.r2,P0.r3,P1.r2,P1.r3]
    //  permlane16_swap(P0',P1'): E=[P0.r0,P0.r2,P1.r0,P1.r2], Od=[P0.r1,P0.r3,P1.r1,P1.r3]
    //  E/Od are exactly A-frag dwords {0,1}/{2,3}. ----
#pragma unroll
    for (int c = 0; c < 2; ++c) {
      bf16x8 pf[2];
#pragma unroll
      for (int g = 0; g < 2; ++g) {
        u32x4 pw;
#pragma unroll
        for (int h = 0; h < 2; ++h) {
          u32 pa = W[g][2 * c][h], pb = W[g][2 * c + 1][h];
          asm("v_permlane32_swap_b32 %0, %1" : "+v"(pa), "+v"(pb));
          asm("v_permlane16_swap_b32 %0, %1" : "+v"(pa), "+v"(pb));
          pw[h]     = pa;   // E  -> dwords 0 (lo) / 1 (hi)
          pw[2 + h] = pb;   // Od -> dwords 2 (lo) / 3 (hi)
        }
        pf[g] = __builtin_bit_cast(bf16x8, pw);
      }
      // ---- O += P V: each vf read feeds BOTH q-groups ----
      __builtin_amdgcn_s_setprio(1);
#pragma unroll
      for (int n = 0; n < 8; ++n) {
        bf16x8 vf = *(const bf16x8*)&Vlds[n * 16 + l16][c * 32 + quad * 8];
        oacc[0][n] = __builtin_amdgcn_mfma_f32_16x16x32_bf16(pf[0], vf, oacc[0][n], 0, 0, 0);
        oacc[1][n] = __builtin_amdgcn_mfma_f32_16x16x32_bf16(pf[1], vf, oacc[1][n], 0, 0, 0);
      }
      __builtin_amdgcn_s_setprio(0);
    }
  }

  // ---- epilogue: lsum holds per-lane partial for q=l16; reduce across quads,
  //      gather each output row's denominator, normalize, store ----
#pragma unroll
  for (int g = 0; g < 2; ++g) {
    float s = lsum[g];
    s += __shfl_xor(s, 16);
    s += __shfl_xor(s, 32);         // every lane: full denom for q = its l16
    float linv[4];
#pragma unroll
    for (int r = 0; r < 4; ++r)
      linv[r] = 1.0f / __shfl(s, quad * 4 + r);  // oacc row q = quad*4+r
#pragma unroll
    for (int n = 0; n < 8; ++n) {
#pragma unroll
      for (int r = 0; r < 4; ++r) {
        int qg = q0 + w * 32 + g * 16 + quad * 4 + r;
        Op[(size_t)qg * DVC + n * 16 + l16] = oacc[g][n][r] * linv[r];
      }
    }
  }
}

extern "C" void kernel_launch(void* const* d_in, const int* in_sizes, int n_in,
                              void* d_out, int out_size, void* d_ws, size_t ws_size,
                              hipStream_t stream) {
  const float* Q = (const float*)d_in[0];
  const float* K = (const float*)d_in[1];
  const float* V = (const float*)d_in[2];
  // d_in[3] is the causal tril mask; causality is applied analytically.
  float* O = (float*)d_out;
  dim3 grid(1024);   // 64 bh * 16 q-tiles (BM=128), XCD-swizzled in-kernel
  fa_kernel<<<grid, 256, 0, stream>>>(Q, K, V, O);
}

// Round 7
// 322.980 us; speedup vs baseline: 1.1582x; 1.1582x over previous
//
#include <hip/hip_runtime.h>
#include <hip/hip_bf16.h>

// Causal flash attention, B=4 H=16 S=2048 DK=DV=128, fp32 in/out, bf16 MFMA compute.
// R8 (resubmit; previous bench died on infra): 8-wave blocks (512 thr, BM=256).
// Occupancy was pinned at ~13% = 1 block/CU (4 waves, 1 wave/SIMD) across
// R4/R6/R7 -- inter-block co-residency never happens (combined VGPR+AGPR
// likely >128/wave). So put the second wave-per-SIMD INSIDE the block: 8 waves
// x 32 q-rows = 256-row q-tile, per-wave inner loop identical to R6's proven
// schedule (in-register P transpose via cvt_pk_bf16 + permlane32/16_swap,
// K double-buffer + cross-barrier prefetch, lgkmcnt-only drains). Staging split
// over 8 waves (kx[4]/vx[4]: pressure DROPS). Per-wave early-exit on tiles
// above the wave's diagonal (barriers still hit). LDS 53248 B.

#define S_LEN 2048
#define DKC   128
#define DVC   128
#define BM    256   // q rows per block (32 per wave, 8 waves)
#define BN    64
#define KPAD  136   // K LDS row stride (bf16): 272B -> b128-aligned reads, 2-way banks
#define VPAD  72    // Vt LDS row stride:      144B -> b128-aligned reads, 2-way banks

typedef __bf16 bf16;
typedef bf16  bf16x4 __attribute__((ext_vector_type(4)));
typedef bf16  bf16x8 __attribute__((ext_vector_type(8)));
typedef float f32x4  __attribute__((ext_vector_type(4)));
typedef unsigned int u32;
typedef u32 u32x4 __attribute__((ext_vector_type(4)));

__global__ __launch_bounds__(512, 2)
void fa_kernel(const float* __restrict__ Q, const float* __restrict__ K,
               const float* __restrict__ V, float* __restrict__ O) {
  __shared__ bf16 Klds[2][BN][KPAD];     // double-buffered [key][d]
  __shared__ bf16 Vlds[DVC][VPAD];       // transposed: [dv][key], single buffer

  const int tid  = threadIdx.x;
  const int w    = tid >> 6;             // 0..7
  const int lane = tid & 63;
  const int quad = lane >> 4;
  const int l16  = lane & 15;

  // XCD pinning (lin%8) + heavy-first (LPT) q-tile order within each bh group.
  const int lin = blockIdx.x;            // 0..511
  const int xcd = lin & 7;
  const int idx = lin >> 3;              // 0..63
  const int qt  = 7 - (idx & 7);         // 7..0, heavy first
  const int bh  = xcd + 8 * (idx >> 3);  // 0..63

  const int q0 = qt * BM;
  const size_t base = (size_t)bh * S_LEN * DKC;
  const float* Qp = Q + base;
  const float* Kp = K + base;
  const float* Vp = V + base;
  float*       Op = O + base;

  const float SCALE2 = 0.08838834764831845f * 1.4426950408889634f; // 1/sqrt(128)*log2e

  // ---- Q fragments, 2 groups of 16 rows (B-layout for swapped QK^T:
  //      lane holds Q[q=l16][k=quad*8+j], which is B[k][q] with col=q=l16) ----
  bf16x8 qf[2][4];
#pragma unroll
  for (int g = 0; g < 2; ++g) {
    const float* qrow = Qp + (size_t)(q0 + w * 32 + g * 16 + l16) * DKC;
#pragma unroll
    for (int c = 0; c < 4; ++c) {
      const float* pq = qrow + c * 32 + quad * 8;
      float4 x = *(const float4*)pq;
      float4 y = *(const float4*)(pq + 4);
      bf16x8 f;
      f[0] = (bf16)(x.x * SCALE2); f[1] = (bf16)(x.y * SCALE2);
      f[2] = (bf16)(x.z * SCALE2); f[3] = (bf16)(x.w * SCALE2);
      f[4] = (bf16)(y.x * SCALE2); f[5] = (bf16)(y.y * SCALE2);
      f[6] = (bf16)(y.z * SCALE2); f[7] = (bf16)(y.w * SCALE2);
      qf[g][c] = f;
    }
  }

  f32x4 oacc[2][8];
#pragma unroll
  for (int g = 0; g < 2; ++g)
#pragma unroll
    for (int n = 0; n < 8; ++n)
#pragma unroll
      for (int r = 0; r < 4; ++r) oacc[g][n][r] = 0.0f;
  float lsum[2] = {0.0f, 0.0f};   // per-lane denominator for q = l16 (per g-group)

  // staging addresses (512 threads: 4 K loads + 4 V loads each)
  const int krow = tid >> 5;          // 0..15 (+ i*16)
  const int kcol = (tid & 31) * 4;    // 0..124
  const int vk   = tid & 31;          // + 32*(i&1)
  const int vd   = tid >> 5;          // 0..15 (+ 16*(i>>1)) -> d/4 index

  const int ntiles = 4 * qt + 4;

  // ---- prologue: issue tile-0 staging loads ----
  float4 kx[4], vx[4];
#pragma unroll
  for (int i = 0; i < 4; ++i)
    kx[i] = *(const float4*)(Kp + (size_t)(krow + i * 16) * DKC + kcol);
#pragma unroll
  for (int i = 0; i < 4; ++i) {
    int k  = vk + 32 * (i & 1);
    int d4 = (vd + 16 * (i >> 1)) * 4;
    vx[i] = *(const float4*)(Vp + (size_t)k * DVC + d4);
  }

  for (int t = 0; t < ntiles; ++t) {
    const int buf = t & 1;
    const int kvb = t * BN;
    // wave-local: does this wave's 32-row band still need tile t?
    const bool active    = (kvb <= q0 + w * 32 + 31);
    const bool need_mask = active && (kvb + BN - 1 > q0 + w * 32);

    // ---- K write (pre-barrier is safe: other waves read the OTHER K buffer) ----
#pragma unroll
    for (int i = 0; i < 4; ++i) {
      bf16x4 k4;
      k4[0] = (bf16)kx[i].x; k4[1] = (bf16)kx[i].y;
      k4[2] = (bf16)kx[i].z; k4[3] = (bf16)kx[i].w;
      *(bf16x4*)&Klds[buf][krow + i * 16][kcol] = k4;
    }
    // ---- K prefetch t+1: stays in flight across the raw barriers below ----
    if (t + 1 < ntiles) {
      const int kvb2 = kvb + BN;
#pragma unroll
      for (int i = 0; i < 4; ++i)
        kx[i] = *(const float4*)(Kp + (size_t)(kvb2 + krow + i * 16) * DKC + kcol);
    }
    // barrier1: all waves done with compute(t-1) (V reads) and K writes visible.
    // lgkmcnt-only drain: do NOT drain vmcnt (prefetch must survive).
    asm volatile("s_waitcnt lgkmcnt(0)\n\ts_barrier" ::: "memory");

    // ---- V write (single buffer; compiler emits a COUNTED vmcnt wait for vx) ----
#pragma unroll
    for (int i = 0; i < 4; ++i) {
      int k  = vk + 32 * (i & 1);
      int d4 = (vd + 16 * (i >> 1)) * 4;
      Vlds[d4 + 0][k] = (bf16)vx[i].x;
      Vlds[d4 + 1][k] = (bf16)vx[i].y;
      Vlds[d4 + 2][k] = (bf16)vx[i].z;
      Vlds[d4 + 3][k] = (bf16)vx[i].w;
    }
    // barrier2: V writes visible before any wave reads the tile.
    asm volatile("s_waitcnt lgkmcnt(0)\n\ts_barrier" ::: "memory");

    // ---- V prefetch t+1 (latency hidden under QK^T + softmax + PV) ----
    if (t + 1 < ntiles) {
      const int kvb2 = kvb + BN;
#pragma unroll
      for (int i = 0; i < 4; ++i) {
        int k  = vk + 32 * (i & 1);
        int d4 = (vd + 16 * (i >> 1)) * 4;
        vx[i] = *(const float4*)(Vp + (size_t)(kvb2 + k) * DVC + d4);
      }
    }

    if (active) {
      // ---- S^T = K Q^T (swapped): per n-subtile, col=q=l16, row=key=quad*4+r.
      //      Fused mask + exp2 + denominator + bf16 pack (sacc lives 8 regs). ----
      u32 W[2][4][2];   // packed bf16 P: [g][n][lo/hi], quad holds keys quad*4+0..3
#pragma unroll
      for (int n = 0; n < 4; ++n) {
        f32x4 sacc[2];
#pragma unroll
        for (int g = 0; g < 2; ++g)
#pragma unroll
          for (int r = 0; r < 4; ++r) sacc[g][r] = 0.0f;
#pragma unroll
        for (int c = 0; c < 4; ++c) {
          bf16x8 kf = *(const bf16x8*)&Klds[buf][n * 16 + l16][c * 32 + quad * 8];
          sacc[0] = __builtin_amdgcn_mfma_f32_16x16x32_bf16(kf, qf[0][c], sacc[0], 0, 0, 0);
          sacc[1] = __builtin_amdgcn_mfma_f32_16x16x32_bf16(kf, qf[1][c], sacc[1], 0, 0, 0);
        }
        if (need_mask) {
          const int kg = kvb + n * 16 + quad * 4;
#pragma unroll
          for (int g = 0; g < 2; ++g) {
            const int qg = q0 + w * 32 + g * 16 + l16;
#pragma unroll
            for (int r = 0; r < 4; ++r)
              if (kg + r > qg) sacc[g][r] = -1e30f;  // exp2 -> 0
          }
        }
#pragma unroll
        for (int g = 0; g < 2; ++g) {
          float p0 = exp2f(sacc[g][0]);
          float p1 = exp2f(sacc[g][1]);
          float p2 = exp2f(sacc[g][2]);
          float p3 = exp2f(sacc[g][3]);
          lsum[g] += (p0 + p1) + (p2 + p3);
          asm("v_cvt_pk_bf16_f32 %0, %1, %2" : "=v"(W[g][n][0]) : "v"(p0), "v"(p1));
          asm("v_cvt_pk_bf16_f32 %0, %1, %2" : "=v"(W[g][n][1]) : "v"(p2), "v"(p3));
        }
      }

      // ---- P: C-layout -> A-layout IN REGISTERS (no LDS round-trip).
      //  permlane32_swap: P0'=[P0.r0,P0.r1,P1.r0,P1.r1], P1'=[P0.r2,P0.r3,P1.r2,P1.r3]
      //  permlane16_swap: E=[P0.r0,P0.r2,P1.r0,P1.r2], Od=[P0.r1,P0.r3,P1.r1,P1.r3]
      //  E/Od are exactly A-frag dwords {0,1}/{2,3}. ----
#pragma unroll
      for (int c = 0; c < 2; ++c) {
        bf16x8 pf[2];
#pragma unroll
        for (int g = 0; g < 2; ++g) {
          u32x4 pw;
#pragma unroll
          for (int h = 0; h < 2; ++h) {
            u32 pa = W[g][2 * c][h], pb = W[g][2 * c + 1][h];
            asm("v_permlane32_swap_b32 %0, %1" : "+v"(pa), "+v"(pb));
            asm("v_permlane16_swap_b32 %0, %1" : "+v"(pa), "+v"(pb));
            pw[h]     = pa;   // E  -> dwords 0 (lo) / 1 (hi)
            pw[2 + h] = pb;   // Od -> dwords 2 (lo) / 3 (hi)
          }
          pf[g] = __builtin_bit_cast(bf16x8, pw);
        }
        // ---- O += P V: each vf read feeds BOTH q-groups ----
#pragma unroll
        for (int n = 0; n < 8; ++n) {
          bf16x8 vf = *(const bf16x8*)&Vlds[n * 16 + l16][c * 32 + quad * 8];
          oacc[0][n] = __builtin_amdgcn_mfma_f32_16x16x32_bf16(pf[0], vf, oacc[0][n], 0, 0, 0);
          oacc[1][n] = __builtin_amdgcn_mfma_f32_16x16x32_bf16(pf[1], vf, oacc[1][n], 0, 0, 0);
        }
      }
    }
  }

  // ---- epilogue: lsum holds per-lane partial for q=l16; reduce across quads,
  //      gather each output row's denominator, normalize, store ----
#pragma unroll
  for (int g = 0; g < 2; ++g) {
    float s = lsum[g];
    s += __shfl_xor(s, 16);
    s += __shfl_xor(s, 32);         // every lane: full denom for q = its l16
    float linv[4];
#pragma unroll
    for (int r = 0; r < 4; ++r)
      linv[r] = 1.0f / __shfl(s, quad * 4 + r);  // oacc row q = quad*4+r
#pragma unroll
    for (int n = 0; n < 8; ++n) {
#pragma unroll
      for (int r = 0; r < 4; ++r) {
        int qg = q0 + w * 32 + g * 16 + quad * 4 + r;
        Op[(size_t)qg * DVC + n * 16 + l16] = oacc[g][n][r] * linv[r];
      }
    }
  }
}

extern "C" void kernel_launch(void* const* d_in, const int* in_sizes, int n_in,
                              void* d_out, int out_size, void* d_ws, size_t ws_size,
                              hipStream_t stream) {
  const float* Q = (const float*)d_in[0];
  const float* K = (const float*)d_in[1];
  const float* V = (const float*)d_in[2];
  // d_in[3] is the causal tril mask; causality is applied analytically.
  float* O = (float*)d_out;
  dim3 grid(512);   // 64 bh * 8 q-tiles (BM=256), XCD-pinned, heavy-first (LPT)
  fa_kernel<<<grid, 512, 0, stream>>>(Q, K, V, O);
}